// Round 1
// baseline (1088.795 us; speedup 1.0000x reference)
//
#include <hip/hip_runtime.h>
#include <math.h>

namespace {
constexpr int B_ = 32;
constexpr int I_ = 2048;
constexpr int J_ = 64;
constexpr int D_ = 8;
constexpr int E_ = 16;
constexpr int BH = 2;                     // batch halves per i
constexpr int BB = B_ / BH;               // 16 batches per pass-block
constexpr int WAVES = 8;
constexpr int THREADS = WAVES * 64;       // 512
constexpr int IPW = 2;                    // i per wave
constexpr int IPB = WAVES * IPW;          // 16 i per block
constexpr int NIC = I_ / IPB;             // 128 i-chunks
constexpr int PASS_BLOCKS = NIC * BH;     // 256 blocks (1 per CU)
constexpr int PART_STRIDE = BB * J_ * E_; // 16384 floats per pass-block
constexpr int VSZ = B_ * J_ * E_;         // 32768 floats
}

// One routing pass. MODE 0: uniform coupling c=1/64 (iteration 1, b-logits all
// zero). MODE 1: logits = dot(uhat, v) (v = v1 for iter 2, v1+v2 for iter 3).
// Wave owns one i; lane = j. W[i,j,:,:] kept in 128 VGPRs, reused over 16 b's.
// Partial s accumulated in LDS [bb][e][j] via ds_add_f32 (lane=j -> 2-way bank
// aliasing, free), then dumped coalesced as partial[block][bb][j][e].
template <int MODE>
__global__ __launch_bounds__(THREADS, 2) void caps_pass(
    const float* __restrict__ x, const float* __restrict__ W,
    const float* __restrict__ v, float* __restrict__ partial) {
  __shared__ float spart[BB * E_ * J_];  // 64 KiB, [bb][e][j]
  const int tid = threadIdx.x;
  for (int k = tid; k < BB * E_ * J_; k += THREADS) spart[k] = 0.0f;
  const int ic = blockIdx.x >> 1;
  const int bh = blockIdx.x & 1;
  const int wv = tid >> 6;
  const int j = tid & 63;
  __syncthreads();

#pragma unroll 1
  for (int ii = 0; ii < IPW; ++ii) {
    const int i = ic * IPB + wv * IPW + ii;
    // W[i, j, :, :] -> 128 registers
    float w[D_ * E_];
    {
      const float4* wp =
          reinterpret_cast<const float4*>(W + (size_t)(i * J_ + j) * (D_ * E_));
#pragma unroll
      for (int k = 0; k < (D_ * E_) / 4; ++k) {
        const float4 t = wp[k];
        w[4 * k + 0] = t.x;
        w[4 * k + 1] = t.y;
        w[4 * k + 2] = t.z;
        w[4 * k + 3] = t.w;
      }
    }
#pragma unroll 1
    for (int bb = 0; bb < BB; ++bb) {
      const int b = bh * BB + bb;
      float xs[D_];
      {
        const float4* xp =
            reinterpret_cast<const float4*>(x + ((size_t)b * I_ + i) * D_);
        const float4 t0 = xp[0], t1 = xp[1];
        xs[0] = t0.x; xs[1] = t0.y; xs[2] = t0.z; xs[3] = t0.w;
        xs[4] = t1.x; xs[5] = t1.y; xs[6] = t1.z; xs[7] = t1.w;
      }
      // uhat[j, e] for this (b, i): 128 FMA
      float uh[E_];
#pragma unroll
      for (int e = 0; e < E_; ++e) uh[e] = 0.0f;
#pragma unroll
      for (int d = 0; d < D_; ++d) {
#pragma unroll
        for (int e = 0; e < E_; ++e) uh[e] = fmaf(xs[d], w[d * E_ + e], uh[e]);
      }
      float c;
      if (MODE == 0) {
        c = 1.0f / 64.0f;
      } else {
        float vv[E_];
        const float4* vp =
            reinterpret_cast<const float4*>(v + ((size_t)b * J_ + j) * E_);
#pragma unroll
        for (int q = 0; q < 4; ++q) {
          const float4 t = vp[q];
          vv[4 * q + 0] = t.x; vv[4 * q + 1] = t.y;
          vv[4 * q + 2] = t.z; vv[4 * q + 3] = t.w;
        }
        float l0 = 0.f, l1 = 0.f, l2 = 0.f, l3 = 0.f;
#pragma unroll
        for (int e = 0; e < E_; e += 4) {
          l0 = fmaf(uh[e + 0], vv[e + 0], l0);
          l1 = fmaf(uh[e + 1], vv[e + 1], l1);
          l2 = fmaf(uh[e + 2], vv[e + 2], l2);
          l3 = fmaf(uh[e + 3], vv[e + 3], l3);
        }
        const float lg = (l0 + l1) + (l2 + l3);
        // softmax over j == softmax across the 64 lanes
        float m = lg;
#pragma unroll
        for (int off = 32; off > 0; off >>= 1)
          m = fmaxf(m, __shfl_xor(m, off));
        const float p = __expf(lg - m);
        float sm = p;
#pragma unroll
        for (int off = 32; off > 0; off >>= 1) sm += __shfl_xor(sm, off);
        c = p / sm;
      }
      float* sp = spart + j;
#pragma unroll
      for (int e = 0; e < E_; ++e)
        atomicAdd(sp + (bb * E_ + e) * J_, c * uh[e]);
    }
  }
  __syncthreads();
  // dump LDS accumulator -> global partial[block][bb][j][e] (coalesced stores;
  // the [e][j]->[j][e] LDS transpose-read conflict is one-time, negligible)
  float* outp = partial + (size_t)blockIdx.x * PART_STRIDE;
  for (int k = tid; k < PART_STRIDE; k += THREADS) {
    const int e = k & (E_ - 1);
    const int jj = (k >> 4) & (J_ - 1);
    const int bb = k >> 10;
    outp[k] = spart[(bb * E_ + e) * J_ + jj];
  }
}

// Reduce the 128 i-chunk partials for one (b, j-octet), squash, emit v.
// mode 0: v1 = squash(s); vsum = v1
// mode 1: vsum += squash(s)           (vsum = v1 + v2 for iteration 3 logits)
// mode 2: out = squash(s)             (final output)
__global__ __launch_bounds__(128) void caps_reduce(
    const float* __restrict__ partial, float* __restrict__ v1,
    float* __restrict__ vsum, float* __restrict__ out, const int mode) {
  const int b = blockIdx.x >> 3;
  const int jg = blockIdx.x & 7;
  const int t = threadIdx.x;  // t = j8*16 + e  (lanes: (j,e) contiguous)
  const int e = t & (E_ - 1);
  const int j = jg * 8 + (t >> 4);
  const int bh = b >> 4;
  const int bb = b & (BB - 1);
  const float* p =
      partial + (size_t)bh * PART_STRIDE + (size_t)bb * (J_ * E_) + j * E_ + e;
  float s = 0.0f;
#pragma unroll 8
  for (int icb = 0; icb < NIC; ++icb)
    s += p[(size_t)icb * (BH * PART_STRIDE)];
  // squash: norm over e (16-lane shuffle groups)
  float sq = s * s;
  sq += __shfl_xor(sq, 1);
  sq += __shfl_xor(sq, 2);
  sq += __shfl_xor(sq, 4);
  sq += __shfl_xor(sq, 8);
  const float scale = sq / ((1.0f + sq) * sqrtf(sq));
  const float vv = s * scale;
  const int idx = (b * J_ + j) * E_ + e;
  if (mode == 0) {
    v1[idx] = vv;
    vsum[idx] = vv;
  } else if (mode == 1) {
    vsum[idx] += vv;
  } else {
    out[idx] = vv;
  }
}

extern "C" void kernel_launch(void* const* d_in, const int* in_sizes, int n_in,
                              void* d_out, int out_size, void* d_ws,
                              size_t ws_size, hipStream_t stream) {
  const float* x = (const float*)d_in[0];
  const float* W = (const float*)d_in[1];
  float* out = (float*)d_out;
  float* partial = (float*)d_ws;                          // 16 MiB
  float* v1 = partial + (size_t)PASS_BLOCKS * PART_STRIDE;
  float* vsum = v1 + VSZ;

  // iteration 1: c uniform -> s1 -> v1 (vsum = v1)
  caps_pass<0><<<PASS_BLOCKS, THREADS, 0, stream>>>(x, W, nullptr, partial);
  caps_reduce<<<B_ * 8, 128, 0, stream>>>(partial, v1, vsum, out, 0);
  // iteration 2: logits = dot(uhat, v1) -> v2 (vsum = v1 + v2)
  caps_pass<1><<<PASS_BLOCKS, THREADS, 0, stream>>>(x, W, v1, partial);
  caps_reduce<<<B_ * 8, 128, 0, stream>>>(partial, v1, vsum, out, 1);
  // iteration 3: logits = dot(uhat, v1+v2) -> v3 = output
  caps_pass<1><<<PASS_BLOCKS, THREADS, 0, stream>>>(x, W, vsum, partial);
  caps_reduce<<<B_ * 8, 128, 0, stream>>>(partial, v1, vsum, out, 2);
}

// Round 2
// 148.676 us; speedup vs baseline: 7.3233x; 7.3233x over previous
//
#include <hip/hip_runtime.h>
#include <math.h>

namespace {
constexpr int B_ = 32, I_ = 2048, J_ = 64, D_ = 8, E_ = 16;
constexpr int THREADS = 512;                 // 8 waves
constexpr int BPW = 2;                       // batches per wave (reg accum)
constexpr int BBLK = 16;                     // batches per block (8 waves * 2)
constexpr int BH = B_ / BBLK;                // 2 batch-halves
constexpr int NI = 16;                       // i's per block
constexpr int NIC = I_ / NI;                 // 128 i-chunks
constexpr int PASS_BLOCKS = NIC * BH;        // 256 blocks
constexpr int PART_STRIDE = BBLK * J_ * E_;  // 16384 floats per block
constexpr int VSZ = B_ * J_ * E_;            // 32768
constexpr int WTILE = J_ * D_ * E_;          // 8192 floats = 32 KB per W[i]
constexpr int WQ = WTILE / 4;                // 2048 quads
}

// async global->LDS, 16B per lane. LDS dest is wave-uniform base + lane*16
// (linear); the swizzle lives in the PRE-PERMUTED global source address
// (both-sides rule: LDS[p] = Wtile[p ^ ((p>>5)&7)], read applies same XOR).
__device__ __forceinline__ void gload_lds16(const float* g, float* l) {
  __builtin_amdgcn_global_load_lds(
      (const __attribute__((address_space(1))) void*)g,
      (__attribute__((address_space(3))) void*)l, 16, 0, 0);
}

// One routing pass, no atomics. Wave owns 2 batches; lane = j. W[i] staged in
// double-buffered LDS (XOR-swizzled rows so lane-j b128 reads are bank-uniform)
// and consumed by all 16 batches of the block. acc in VGPRs; partials to global.
template <int MODE>
__global__ __launch_bounds__(THREADS, 2) void caps_pass(
    const float* __restrict__ x, const float* __restrict__ W,
    const float* __restrict__ v, float* __restrict__ partial) {
  __shared__ float Wlds[2][WQ * 4];  // 2 x 32 KiB
  const int tid = threadIdx.x;
  const int wv = tid >> 6;
  const int j = tid & 63;
  const int ic = (int)blockIdx.x >> 1;
  const int bh = (int)blockIdx.x & 1;
  const int i0 = ic * NI;
  const int b0 = bh * BBLK + 2 * wv;  // this wave's two global batches
  const int sw = j & 7;               // row-swizzle key

  float vv[BPW][E_];
  if (MODE == 1) {
#pragma unroll
    for (int bb = 0; bb < BPW; ++bb) {
      const float4* vp = reinterpret_cast<const float4*>(
          v + ((size_t)(b0 + bb) * J_ + j) * E_);
#pragma unroll
      for (int q = 0; q < 4; ++q) {
        const float4 t = vp[q];
        vv[bb][4 * q + 0] = t.x; vv[bb][4 * q + 1] = t.y;
        vv[bb][4 * q + 2] = t.z; vv[bb][4 * q + 3] = t.w;
      }
    }
  }

  float acc[BPW][E_];
#pragma unroll
  for (int bb = 0; bb < BPW; ++bb)
#pragma unroll
    for (int e = 0; e < E_; ++e) acc[bb][e] = 0.0f;

  // prologue: stage W[i0] into buffer 0 (8 waves x 4 instr x 64 lanes = 2048 q)
  {
    const float* Wt = W + (size_t)i0 * WTILE;
#pragma unroll
    for (int it = 0; it < 4; ++it) {
      const int p = (wv * 4 + it) * 64 + j;
      const int src = p ^ ((p >> 5) & 7);
      gload_lds16(Wt + (size_t)src * 4, &Wlds[0][p * 4]);
    }
  }
  __syncthreads();  // emits vmcnt(0) drain + barrier

#pragma unroll 1
  for (int t = 0; t < NI; ++t) {
    const int cur = t & 1;
    if (t + 1 < NI) {  // stage next tile into the other buffer
      const float* Wt = W + (size_t)(i0 + t + 1) * WTILE;
#pragma unroll
      for (int it = 0; it < 4; ++it) {
        const int p = (wv * 4 + it) * 64 + j;
        const int src = p ^ ((p >> 5) & 7);
        gload_lds16(Wt + (size_t)src * 4, &Wlds[cur ^ 1][p * 4]);
      }
    }
    const int i = i0 + t;
    float xs[BPW][D_];
#pragma unroll
    for (int bb = 0; bb < BPW; ++bb) {
      const float4* xp = reinterpret_cast<const float4*>(
          x + ((size_t)(b0 + bb) * I_ + i) * D_);
      const float4 t0 = xp[0], t1 = xp[1];
      xs[bb][0] = t0.x; xs[bb][1] = t0.y; xs[bb][2] = t0.z; xs[bb][3] = t0.w;
      xs[bb][4] = t1.x; xs[bb][5] = t1.y; xs[bb][6] = t1.z; xs[bb][7] = t1.w;
    }

    float uh[BPW][E_];
#pragma unroll
    for (int bb = 0; bb < BPW; ++bb)
#pragma unroll
      for (int e = 0; e < E_; ++e) uh[bb][e] = 0.0f;

    const float* buf = Wlds[cur];
    const int rowbase = j * 32;
#pragma unroll
    for (int k = 0; k < 32; ++k) {
      const float4 quad = *reinterpret_cast<const float4*>(
          buf + (size_t)(rowbase + (k ^ sw)) * 4);
      const int d = k >> 2;
      const int e0 = (k & 3) * 4;
#pragma unroll
      for (int bb = 0; bb < BPW; ++bb) {
        uh[bb][e0 + 0] = fmaf(xs[bb][d], quad.x, uh[bb][e0 + 0]);
        uh[bb][e0 + 1] = fmaf(xs[bb][d], quad.y, uh[bb][e0 + 1]);
        uh[bb][e0 + 2] = fmaf(xs[bb][d], quad.z, uh[bb][e0 + 2]);
        uh[bb][e0 + 3] = fmaf(xs[bb][d], quad.w, uh[bb][e0 + 3]);
      }
    }

    float c[BPW];
    if (MODE == 0) {
      c[0] = 1.0f / 64.0f;
      c[1] = 1.0f / 64.0f;
    } else {
#pragma unroll
      for (int bb = 0; bb < BPW; ++bb) {
        float l0 = 0.f, l1 = 0.f, l2 = 0.f, l3 = 0.f;
#pragma unroll
        for (int e = 0; e < E_; e += 4) {
          l0 = fmaf(uh[bb][e + 0], vv[bb][e + 0], l0);
          l1 = fmaf(uh[bb][e + 1], vv[bb][e + 1], l1);
          l2 = fmaf(uh[bb][e + 2], vv[bb][e + 2], l2);
          l3 = fmaf(uh[bb][e + 3], vv[bb][e + 3], l3);
        }
        const float lg = (l0 + l1) + (l2 + l3);
        // |lg| <~ 8 -> expf safe without max-subtraction (fp32 range huge)
        const float p = __expf(lg);
        float s = p;
#pragma unroll
        for (int off = 1; off < 64; off <<= 1) s += __shfl_xor(s, off);
        c[bb] = p / s;
      }
    }
#pragma unroll
    for (int bb = 0; bb < BPW; ++bb)
#pragma unroll
      for (int e = 0; e < E_; ++e)
        acc[bb][e] = fmaf(c[bb], uh[bb][e], acc[bb][e]);
    __syncthreads();  // buf[cur^1] staged; everyone done reading buf[cur]
  }

  // partial[block][blocal][j][e], blocal = 2*wv + bb
  float* outp = partial + (size_t)blockIdx.x * PART_STRIDE +
                ((size_t)(2 * wv) * J_ + j) * E_;
#pragma unroll
  for (int bb = 0; bb < BPW; ++bb) {
#pragma unroll
    for (int q = 0; q < 4; ++q) {
      float4 t;
      t.x = acc[bb][4 * q + 0]; t.y = acc[bb][4 * q + 1];
      t.z = acc[bb][4 * q + 2]; t.w = acc[bb][4 * q + 3];
      *reinterpret_cast<float4*>(outp + (size_t)bb * (J_ * E_) + q * 4) = t;
    }
  }
}

// Reduce the 128 i-chunk partials for one (b, j-octet), squash, emit v.
// mode 0: v1 = squash(s); vsum = v1
// mode 1: vsum += squash(s)
// mode 2: out = squash(s)
__global__ __launch_bounds__(128) void caps_reduce(
    const float* __restrict__ partial, float* __restrict__ v1,
    float* __restrict__ vsum, float* __restrict__ out, const int mode) {
  const int b = blockIdx.x >> 3;
  const int jg = blockIdx.x & 7;
  const int t = threadIdx.x;
  const int e = t & (E_ - 1);
  const int j = jg * 8 + (t >> 4);
  const int bh = b >> 4;
  const int bb = b & (BBLK - 1);
  const float* p =
      partial + (size_t)bh * PART_STRIDE + (size_t)bb * (J_ * E_) + j * E_ + e;
  float s = 0.0f;
#pragma unroll 8
  for (int icb = 0; icb < NIC; ++icb)
    s += p[(size_t)icb * (BH * PART_STRIDE)];
  float sq = s * s;
  sq += __shfl_xor(sq, 1);
  sq += __shfl_xor(sq, 2);
  sq += __shfl_xor(sq, 4);
  sq += __shfl_xor(sq, 8);
  const float scale = sq / ((1.0f + sq) * sqrtf(sq));
  const float vv = s * scale;
  const int idx = (b * J_ + j) * E_ + e;
  if (mode == 0) {
    v1[idx] = vv;
    vsum[idx] = vv;
  } else if (mode == 1) {
    vsum[idx] += vv;
  } else {
    out[idx] = vv;
  }
}

extern "C" void kernel_launch(void* const* d_in, const int* in_sizes, int n_in,
                              void* d_out, int out_size, void* d_ws,
                              size_t ws_size, hipStream_t stream) {
  const float* x = (const float*)d_in[0];
  const float* W = (const float*)d_in[1];
  float* out = (float*)d_out;
  float* partial = (float*)d_ws;  // 16 MiB
  float* v1 = partial + (size_t)PASS_BLOCKS * PART_STRIDE;
  float* vsum = v1 + VSZ;

  // iteration 1: uniform c -> v1 (vsum = v1)
  caps_pass<0><<<PASS_BLOCKS, THREADS, 0, stream>>>(x, W, nullptr, partial);
  caps_reduce<<<B_ * 8, 128, 0, stream>>>(partial, v1, vsum, out, 0);
  // iteration 2: logits = dot(uhat, v1) -> v2 (vsum = v1 + v2)
  caps_pass<1><<<PASS_BLOCKS, THREADS, 0, stream>>>(x, W, v1, partial);
  caps_reduce<<<B_ * 8, 128, 0, stream>>>(partial, v1, vsum, out, 1);
  // iteration 3: logits = dot(uhat, v1 + v2) -> output
  caps_pass<1><<<PASS_BLOCKS, THREADS, 0, stream>>>(x, W, vsum, partial);
  caps_reduce<<<B_ * 8, 128, 0, stream>>>(partial, v1, vsum, out, 2);
}